// Round 1
// baseline (764.463 us; speedup 1.0000x reference)
//
#include <hip/hip_runtime.h>

#define THREADS 256

// ---------------- CSR build ----------------

__global__ void count_kernel(const int* __restrict__ dst, int* __restrict__ cnt, int E) {
  int e = blockIdx.x * blockDim.x + threadIdx.x;
  if (e < E) atomicAdd(&cnt[dst[e]], 1);
}

__global__ void scan1_kernel(const int* __restrict__ cnt, int* __restrict__ bsum, int N) {
  __shared__ int s[THREADS];
  int t = threadIdx.x;
  int base = blockIdx.x * 1024 + t * 4;
  int v = 0;
#pragma unroll
  for (int i = 0; i < 4; ++i) { int idx = base + i; if (idx < N) v += cnt[idx]; }
  s[t] = v; __syncthreads();
  for (int d = 128; d > 0; d >>= 1) { if (t < d) s[t] += s[t + d]; __syncthreads(); }
  if (t == 0) bsum[blockIdx.x] = s[0];
}

__global__ void scan2_kernel(const int* __restrict__ bsum, int* __restrict__ boff,
                             int* __restrict__ rowoff, int NB, int N, int E) {
  __shared__ int s[THREADS];
  int t = threadIdx.x;
  int v = (t < NB) ? bsum[t] : 0;
  s[t] = v; __syncthreads();
  for (int d = 1; d < THREADS; d <<= 1) {
    int x = (t >= d) ? s[t - d] : 0;
    __syncthreads();
    s[t] += x;
    __syncthreads();
  }
  boff[t] = s[t] - v;  // exclusive
  if (t == 0) rowoff[N] = E;
}

__global__ void scan3_kernel(const int* __restrict__ cnt, const int* __restrict__ boff,
                             int* __restrict__ rowoff, float* __restrict__ invdeg, int N) {
  __shared__ int s[THREADS];
  int t = threadIdx.x;
  int base = blockIdx.x * 1024 + t * 4;
  int c[4]; int v = 0;
#pragma unroll
  for (int i = 0; i < 4; ++i) { int idx = base + i; c[i] = (idx < N) ? cnt[idx] : 0; v += c[i]; }
  s[t] = v; __syncthreads();
  for (int d = 1; d < THREADS; d <<= 1) {
    int x = (t >= d) ? s[t - d] : 0;
    __syncthreads();
    s[t] += x;
    __syncthreads();
  }
  int pre = s[t] - v + boff[blockIdx.x];
#pragma unroll
  for (int i = 0; i < 4; ++i) {
    int idx = base + i;
    if (idx < N) {
      rowoff[idx] = pre;
      invdeg[idx] = 1.0f / (float)((c[i] > 1) ? c[i] : 1);
      pre += c[i];
    }
  }
}

__global__ void fill_kernel(const int* __restrict__ src, const int* __restrict__ dst,
                            const int* __restrict__ rowoff, int* __restrict__ cursor,
                            int* __restrict__ adj, int E) {
  int e = blockIdx.x * blockDim.x + threadIdx.x;
  if (e < E) {
    int v = dst[e];
    int pos = atomicAdd(&cursor[v], 1);
    adj[rowoff[v] + pos] = src[e];
  }
}

// ---------------- GEMM: C[N,128] = Acat[N,128] @ Weff[128,128]^T (+bias,relu) --------
// wmode 0 (out-concat): Weff[c][k] = c<64 ? W0[c][k] (W0=[64,128]) : W1[c-64][k]
// wmode 1 (K-concat)  : Weff[c][k] = k<64 ? W0[c][k] (W0=[128,64]) : W1[c][k-64]
// A element k: k<64 -> A0[r*sa0+k], else A1[r*sa1+k-64]
// Output col c: c<64 -> out0[r*so0+c], else out1[r*so1+c-64]

__global__ __launch_bounds__(256) void gemm_kernel(
    const float* __restrict__ A0, const float* __restrict__ A1, int sa0, int sa1,
    const float* __restrict__ W0, const float* __restrict__ W1, int wmode,
    const float* __restrict__ bias, int relu,
    float* __restrict__ out0, float* __restrict__ out1, int so0, int so1, int N)
{
  __shared__ float Wlds[128 * 128];  // Weff[c][k], 64 KB
  int t = threadIdx.x;
  for (int i = t; i < 128 * 128; i += 256) {
    int c = i >> 7, k = i & 127;
    float w;
    if (wmode == 0) w = (c < 64) ? W0[c * 128 + k] : W1[(c - 64) * 128 + k];
    else            w = (k < 64) ? W0[c * 64 + k]  : W1[c * 64 + (k - 64)];
    Wlds[i] = w;
  }
  __syncthreads();

  int rg = t & 31, cg = t >> 5;           // 32 row-groups x 8 col-groups
  int r0 = blockIdx.x * 128 + rg * 4;
  int c0 = cg * 16;
  float acc[4][16];
#pragma unroll
  for (int rr = 0; rr < 4; ++rr)
#pragma unroll
    for (int cc = 0; cc < 16; ++cc) acc[rr][cc] = 0.f;

  for (int k4 = 0; k4 < 32; ++k4) {
    int k = k4 * 4;
    const float* __restrict__ Abase = (k < 64) ? A0 : A1;
    int stride = (k < 64) ? sa0 : sa1;
    int kk = (k < 64) ? k : (k - 64);
    float4 a[4];
#pragma unroll
    for (int rr = 0; rr < 4; ++rr) {
      int r = r0 + rr;
      a[rr] = (r < N) ? *(const float4*)(Abase + (size_t)r * stride + kk)
                      : make_float4(0.f, 0.f, 0.f, 0.f);
    }
#pragma unroll
    for (int cc = 0; cc < 16; ++cc) {
      float4 w = *(const float4*)&Wlds[(c0 + cc) * 128 + k];
#pragma unroll
      for (int rr = 0; rr < 4; ++rr) {
        acc[rr][cc] = fmaf(a[rr].x, w.x, acc[rr][cc]);
        acc[rr][cc] = fmaf(a[rr].y, w.y, acc[rr][cc]);
        acc[rr][cc] = fmaf(a[rr].z, w.z, acc[rr][cc]);
        acc[rr][cc] = fmaf(a[rr].w, w.w, acc[rr][cc]);
      }
    }
  }

  bool half0 = (c0 < 64);
  float* outp = half0 ? out0 : out1;
  int so = half0 ? so0 : so1;
  int cbase = half0 ? c0 : (c0 - 64);
#pragma unroll
  for (int rr = 0; rr < 4; ++rr) {
    int r = r0 + rr;
    if (r >= N) break;
    float vals[16];
#pragma unroll
    for (int cc = 0; cc < 16; ++cc) {
      float v = acc[rr][cc];
      if (bias) v += bias[c0 + cc];
      if (relu) v = fmaxf(v, 0.f);
      vals[cc] = v;
    }
#pragma unroll
    for (int q = 0; q < 4; ++q) {
      float4 o = make_float4(vals[q * 4], vals[q * 4 + 1], vals[q * 4 + 2], vals[q * 4 + 3]);
      *(float4*)(outp + (size_t)r * so + cbase + q * 4) = o;
    }
  }
}

// ---------------- CSR mean-aggregate (64-wide features), fused epilogue -------------
// out[v][lane] = sum_{u in adj[v]} feat[u][lane] * invdeg[v]  (+ add[v][lane]) (+ bias[lane]) (relu?)

__global__ __launch_bounds__(256) void agg_kernel(
    const float* __restrict__ feat, const int* __restrict__ adj,
    const int* __restrict__ rowoff, const float* __restrict__ invdeg,
    const float* __restrict__ add, const float* __restrict__ bias,
    float* __restrict__ out, int N, int relu)
{
  int wid = blockIdx.x * 4 + (threadIdx.x >> 6);  // one wave per node
  int lane = threadIdx.x & 63;                    // lane = feature channel
  if (wid >= N) return;
  int beg = rowoff[wid], end = rowoff[wid + 1];
  float sum = 0.f;
  int j = beg;
  for (; j + 4 <= end; j += 4) {
    int u0 = adj[j], u1 = adj[j + 1], u2 = adj[j + 2], u3 = adj[j + 3];
    sum += feat[u0 * 64 + lane];
    sum += feat[u1 * 64 + lane];
    sum += feat[u2 * 64 + lane];
    sum += feat[u3 * 64 + lane];
  }
  for (; j < end; ++j) sum += feat[adj[j] * 64 + lane];
  float v = sum * invdeg[wid];
  if (add)  v += add[wid * 64 + lane];
  if (bias) v += bias[lane];
  if (relu) v = fmaxf(v, 0.f);
  out[wid * 64 + lane] = v;
}

// ---------------- launch ----------------

extern "C" void kernel_launch(void* const* d_in, const int* in_sizes, int n_in,
                              void* d_out, int out_size, void* d_ws, size_t ws_size,
                              hipStream_t stream) {
  const float* x   = (const float*)d_in[0];
  const int* edges = (const int*)d_in[1];
  const float* Wl1 = (const float*)d_in[2];
  const float* Wr1 = (const float*)d_in[3];
  const float* b1  = (const float*)d_in[4];
  const float* Wl2 = (const float*)d_in[5];
  const float* Wr2 = (const float*)d_in[6];
  const float* b2  = (const float*)d_in[7];
  const float* Wl3 = (const float*)d_in[8];
  const float* Wr3 = (const float*)d_in[9];
  const float* b3  = (const float*)d_in[10];

  int N = in_sizes[0] / 128;
  int E = in_sizes[1] / 2;
  const int* srcp = edges;
  const int* dstp = edges + E;

  char* ws = (char*)d_ws;
  size_t off = 0;
  auto carve = [&](size_t bytes) -> void* {
    void* p = (void*)(ws + off);
    off += (bytes + 255) & ~(size_t)255;
    return p;
  };
  int*   adj    = (int*)carve((size_t)E * 4);
  int*   rowoff = (int*)carve((size_t)(N + 1) * 4);
  int*   cnt    = (int*)carve((size_t)N * 4);
  int*   cursor = (int*)carve((size_t)N * 4);
  int*   bsum   = (int*)carve(256 * 4);
  int*   boff   = (int*)carve(256 * 4);
  float* invdeg = (float*)carve((size_t)N * 4);
  float* Z      = (float*)carve((size_t)N * 64 * 4);
  float* Y      = (float*)carve((size_t)N * 64 * 4);
  float* P      = (float*)carve((size_t)N * 128 * 4);
  (void)ws_size;

  hipMemsetAsync(cnt, 0, (size_t)N * 4, stream);
  hipMemsetAsync(cursor, 0, (size_t)N * 4, stream);

  int NB = (N + 1023) / 1024;
  int gridE = (E + THREADS - 1) / THREADS;

  count_kernel<<<gridE, THREADS, 0, stream>>>(dstp, cnt, E);
  scan1_kernel<<<NB, THREADS, 0, stream>>>(cnt, bsum, N);
  scan2_kernel<<<1, THREADS, 0, stream>>>(bsum, boff, rowoff, NB, N, E);
  scan3_kernel<<<NB, THREADS, 0, stream>>>(cnt, boff, rowoff, invdeg, N);
  fill_kernel<<<gridE, THREADS, 0, stream>>>(srcp, dstp, rowoff, cursor, adj, E);

  int gridG = (N + 127) / 128;
  int gridA = (N + 3) / 4;

  // Layer 1 (transform-first): [z1|y1] = x @ [Wl1|Wr1]^T  -> Z, Y
  gemm_kernel<<<gridG, THREADS, 0, stream>>>(x, x + 64, 128, 128, Wl1, Wr1, 0,
                                             nullptr, 0, Z, Y, 64, 64, N);
  // h1 = relu(mean(z1) + y1 + b1) -> Y
  agg_kernel<<<gridA, THREADS, 0, stream>>>(Z, adj, rowoff, invdeg, Y, b1, Y, N, 1);
  // mean2 = mean(h1) -> Z
  agg_kernel<<<gridA, THREADS, 0, stream>>>(Y, adj, rowoff, invdeg, nullptr, nullptr, Z, N, 0);
  // Layer 2 (aggregate-first): h2 = relu([mean2|h1] @ [Wl2,Wr2]_K^T + b2) -> P
  gemm_kernel<<<gridG, THREADS, 0, stream>>>(Z, Y, 64, 64, Wl2, Wr2, 1,
                                             b2, 1, P, P + 64, 128, 128, N);
  // Layer 3 (transform-first): [z3|y3] = h2 @ [Wl3|Wr3]^T -> Z, Y
  gemm_kernel<<<gridG, THREADS, 0, stream>>>(P, P + 64, 128, 128, Wl3, Wr3, 0,
                                             nullptr, 0, Z, Y, 64, 64, N);
  // out = mean(z3) + y3 + b3
  agg_kernel<<<gridA, THREADS, 0, stream>>>(Z, adj, rowoff, invdeg, Y, b3, (float*)d_out, N, 0);
}

// Round 2
// 380.632 us; speedup vs baseline: 2.0084x; 2.0084x over previous
//
#include <hip/hip_runtime.h>

#define THREADS 256

typedef __attribute__((ext_vector_type(8))) short short8;
typedef __attribute__((ext_vector_type(4))) float f32x4;

__device__ inline unsigned short f2bf(float f) {
  unsigned int u = __float_as_uint(f);
  unsigned int r = u + 0x7fffu + ((u >> 16) & 1u);  // round-to-nearest-even
  return (unsigned short)(r >> 16);
}

// ---------------- CSR build ----------------

__global__ void count_kernel(const int* __restrict__ dst, int* __restrict__ cnt, int E) {
  int e = blockIdx.x * blockDim.x + threadIdx.x;
  if (e < E) atomicAdd(&cnt[dst[e]], 1);
}

__global__ void scan1_kernel(const int* __restrict__ cnt, int* __restrict__ bsum, int N) {
  __shared__ int s[THREADS];
  int t = threadIdx.x;
  int base = blockIdx.x * 1024 + t * 4;
  int v = 0;
#pragma unroll
  for (int i = 0; i < 4; ++i) { int idx = base + i; if (idx < N) v += cnt[idx]; }
  s[t] = v; __syncthreads();
  for (int d = 128; d > 0; d >>= 1) { if (t < d) s[t] += s[t + d]; __syncthreads(); }
  if (t == 0) bsum[blockIdx.x] = s[0];
}

__global__ void scan2_kernel(const int* __restrict__ bsum, int* __restrict__ boff,
                             int* __restrict__ rowoff, int NB, int N, int E) {
  __shared__ int s[THREADS];
  int t = threadIdx.x;
  int v = (t < NB) ? bsum[t] : 0;
  s[t] = v; __syncthreads();
  for (int d = 1; d < THREADS; d <<= 1) {
    int x = (t >= d) ? s[t - d] : 0;
    __syncthreads();
    s[t] += x;
    __syncthreads();
  }
  boff[t] = s[t] - v;  // exclusive
  if (t == 0) rowoff[N] = E;
}

__global__ void scan3_kernel(const int* __restrict__ cnt, const int* __restrict__ boff,
                             int* __restrict__ rowoff, float* __restrict__ invdeg, int N) {
  __shared__ int s[THREADS];
  int t = threadIdx.x;
  int base = blockIdx.x * 1024 + t * 4;
  int c[4]; int v = 0;
#pragma unroll
  for (int i = 0; i < 4; ++i) { int idx = base + i; c[i] = (idx < N) ? cnt[idx] : 0; v += c[i]; }
  s[t] = v; __syncthreads();
  for (int d = 1; d < THREADS; d <<= 1) {
    int x = (t >= d) ? s[t - d] : 0;
    __syncthreads();
    s[t] += x;
    __syncthreads();
  }
  int pre = s[t] - v + boff[blockIdx.x];
#pragma unroll
  for (int i = 0; i < 4; ++i) {
    int idx = base + i;
    if (idx < N) {
      rowoff[idx] = pre;
      invdeg[idx] = 1.0f / (float)((c[i] > 1) ? c[i] : 1);
      pre += c[i];
    }
  }
}

__global__ void fill_kernel(const int* __restrict__ src, const int* __restrict__ dst,
                            const int* __restrict__ rowoff, int* __restrict__ cursor,
                            int* __restrict__ adj, int E) {
  int e = blockIdx.x * blockDim.x + threadIdx.x;
  if (e < E) {
    int v = dst[e];
    int pos = atomicAdd(&cursor[v], 1);
    adj[rowoff[v] + pos] = src[e];
  }
}

// ---------------- MFMA GEMM: C[N,128] = A[N,128] @ Weff[128,128]^T ------------------
// wmode 0 (out-concat): Weff[c][k] = c<64 ? W0[c][k] (W0=[64,128]) : W1[c-64][k]
// wmode 1 (K-concat)  : Weff[c][k] = k<64 ? W0[c][k] (W0=[128,64]) : W1[c][k-64]
// A element k: k<64 -> A0 row + k, else A1 row + (k-64); strides in BYTES.
// a_fp32: A is fp32 (converted to bf16 in-register); else A is bf16.
// Output bf16: col c<64 -> out0[row*so0+c], else out1[row*so1+c-64].

__global__ __launch_bounds__(256) void mfma_gemm(
    const void* __restrict__ A0_, const void* __restrict__ A1_, int sa0b, int sa1b, int a_fp32,
    const float* __restrict__ W0, const float* __restrict__ W1, int wmode,
    const float* __restrict__ bias, int relu,
    unsigned short* __restrict__ out0, unsigned short* __restrict__ out1,
    int so0, int so1, int N)
{
  __shared__ __align__(16) unsigned char Wlds[128 * 256];  // Weff[c][k] bf16, XOR-swizzled
  int t = threadIdx.x;

  // stage W (fp32 global -> bf16 LDS), 2048 chunks of 16B
#pragma unroll
  for (int it = 0; it < 8; ++it) {
    int i = it * 256 + t;
    int c = i >> 4, kg = i & 15;
    const float* src;
    if (wmode == 0) src = (c < 64) ? (W0 + c * 128 + kg * 8) : (W1 + (c - 64) * 128 + kg * 8);
    else            src = (kg < 8) ? (W0 + c * 64 + kg * 8)  : (W1 + c * 64 + (kg - 8) * 8);
    short8 v;
#pragma unroll
    for (int q = 0; q < 8; ++q) v[q] = (short)f2bf(src[q]);
    *(short8*)(&Wlds[c * 256 + ((kg * 16) ^ ((c & 7) << 4))]) = v;
  }
  __syncthreads();

  int w = t >> 6, l = t & 63;
  int lr = l & 15, lk = l >> 4;          // lr = frag row/col, lk = k-group (0..3)
  int r0 = blockIdx.x * 128 + w * 32;    // wave handles 32 rows (2 fragment sets)

  // A fragments: afr[set][kt], lane holds A[row=r0+set*16+lr][k=8*lk + 32*kt .. +8)
  short8 afr[2][4];
#pragma unroll
  for (int set = 0; set < 2; ++set) {
    int row = r0 + set * 16 + lr;
    bool ok = row < N;
    if (a_fp32) {
#pragma unroll
      for (int kt = 0; kt < 4; ++kt) {
        short8 a = {0, 0, 0, 0, 0, 0, 0, 0};
        if (ok) {
          const unsigned char* bp = (const unsigned char*)(kt < 2 ? A0_ : A1_)
                + (size_t)row * (kt < 2 ? sa0b : sa1b) + 32 * lk + 128 * (kt & 1);
          f32x4 f0 = *(const f32x4*)bp;
          f32x4 f1 = *(const f32x4*)(bp + 16);
#pragma unroll
          for (int q = 0; q < 4; ++q) { a[q] = (short)f2bf(f0[q]); a[q + 4] = (short)f2bf(f1[q]); }
        }
        afr[set][kt] = a;
      }
    } else {
#pragma unroll
      for (int kt = 0; kt < 4; ++kt) {
        short8 a = {0, 0, 0, 0, 0, 0, 0, 0};
        if (ok) {
          const unsigned char* bp = (const unsigned char*)(kt < 2 ? A0_ : A1_)
                + (size_t)row * (kt < 2 ? sa0b : sa1b) + 16 * lk + 64 * (kt & 1);
          a = *(const short8*)bp;
        }
        afr[set][kt] = a;
      }
    }
  }

  f32x4 acc[2][8];
#pragma unroll
  for (int s = 0; s < 2; ++s)
#pragma unroll
    for (int c = 0; c < 8; ++c) acc[s][c] = (f32x4){0.f, 0.f, 0.f, 0.f};

#pragma unroll
  for (int ct = 0; ct < 8; ++ct) {
    int c = ct * 16 + lr;
    const unsigned char* rowp = &Wlds[c * 256];
    unsigned swz = (unsigned)((c & 7) << 4);
    short8 bfr[4];
#pragma unroll
    for (int kt = 0; kt < 4; ++kt)
      bfr[kt] = *(const short8*)(rowp + (((unsigned)(16 * lk + 64 * kt)) ^ swz));
#pragma unroll
    for (int kt = 0; kt < 4; ++kt) {
      acc[0][ct] = __builtin_amdgcn_mfma_f32_16x16x32_bf16(afr[0][kt], bfr[kt], acc[0][ct], 0, 0, 0);
      acc[1][ct] = __builtin_amdgcn_mfma_f32_16x16x32_bf16(afr[1][kt], bfr[kt], acc[1][ct], 0, 0, 0);
    }
  }

  // epilogue: D row = r0 + set*16 + lk*4 + j, col = ct*16 + lr  (m89 C/D layout)
#pragma unroll
  for (int set = 0; set < 2; ++set) {
    int rbase = r0 + set * 16 + lk * 4;
#pragma unroll
    for (int ct = 0; ct < 8; ++ct) {
      int col = ct * 16 + lr;
      unsigned short* outp = (col < 64) ? out0 : out1;
      int so = (col < 64) ? so0 : so1;
      int cb = (col < 64) ? col : col - 64;
      float bv = bias ? bias[col] : 0.f;
#pragma unroll
      for (int j = 0; j < 4; ++j) {
        int row = rbase + j;
        if (row < N) {
          float v = acc[set][ct][j] + bv;
          if (relu) v = fmaxf(v, 0.f);
          outp[(size_t)row * so + cb] = f2bf(v);
        }
      }
    }
  }
}

// ---------------- CSR mean-aggregate, bf16 features, 2 nodes per wave ----------------
// out[v][c] = (sum_{u in adj[v]} feat[u][c]) * invdeg[v] (+ add[v][c]) (+ bias[c]) (relu?)
// 32-lane half-wave per node; lane sl handles channels 2*sl, 2*sl+1 (bf16x2 = 4B load).

__global__ __launch_bounds__(256) void agg_bf16(
    const unsigned short* __restrict__ feat, const int* __restrict__ adj,
    const int* __restrict__ rowoff, const float* __restrict__ invdeg,
    const unsigned short* __restrict__ add, const float* __restrict__ bias,
    void* __restrict__ outv, int N, int relu, int out_fp32)
{
  int t = threadIdx.x;
  int lane = t & 63;
  int half = lane >> 5, sl = lane & 31;
  int node = blockIdx.x * 8 + (t >> 6) * 2 + half;
  if (node >= N) return;
  int beg = rowoff[node], end = rowoff[node + 1];
  float s0 = 0.f, s1 = 0.f;
  int j = beg;
  for (; j + 4 <= end; j += 4) {
    int u0 = adj[j], u1 = adj[j + 1], u2 = adj[j + 2], u3 = adj[j + 3];
    unsigned p0 = *(const unsigned*)(feat + u0 * 64 + 2 * sl);
    unsigned p1 = *(const unsigned*)(feat + u1 * 64 + 2 * sl);
    unsigned p2 = *(const unsigned*)(feat + u2 * 64 + 2 * sl);
    unsigned p3 = *(const unsigned*)(feat + u3 * 64 + 2 * sl);
    s0 += __uint_as_float(p0 << 16); s1 += __uint_as_float(p0 & 0xffff0000u);
    s0 += __uint_as_float(p1 << 16); s1 += __uint_as_float(p1 & 0xffff0000u);
    s0 += __uint_as_float(p2 << 16); s1 += __uint_as_float(p2 & 0xffff0000u);
    s0 += __uint_as_float(p3 << 16); s1 += __uint_as_float(p3 & 0xffff0000u);
  }
  for (; j < end; ++j) {
    unsigned p = *(const unsigned*)(feat + adj[j] * 64 + 2 * sl);
    s0 += __uint_as_float(p << 16); s1 += __uint_as_float(p & 0xffff0000u);
  }
  float inv = invdeg[node];
  float v0 = s0 * inv, v1 = s1 * inv;
  if (add) {
    unsigned q = *(const unsigned*)(add + (size_t)node * 64 + 2 * sl);
    v0 += __uint_as_float(q << 16); v1 += __uint_as_float(q & 0xffff0000u);
  }
  if (bias) { v0 += bias[2 * sl]; v1 += bias[2 * sl + 1]; }
  if (relu) { v0 = fmaxf(v0, 0.f); v1 = fmaxf(v1, 0.f); }
  if (out_fp32) {
    float* o = (float*)outv + (size_t)node * 64 + 2 * sl;
    o[0] = v0; o[1] = v1;
  } else {
    unsigned pk = ((unsigned)f2bf(v1) << 16) | (unsigned)f2bf(v0);
    *(unsigned*)((unsigned short*)outv + (size_t)node * 64 + 2 * sl) = pk;
  }
}

// ---------------- launch ----------------

extern "C" void kernel_launch(void* const* d_in, const int* in_sizes, int n_in,
                              void* d_out, int out_size, void* d_ws, size_t ws_size,
                              hipStream_t stream) {
  const float* x   = (const float*)d_in[0];
  const int* edges = (const int*)d_in[1];
  const float* Wl1 = (const float*)d_in[2];
  const float* Wr1 = (const float*)d_in[3];
  const float* b1  = (const float*)d_in[4];
  const float* Wl2 = (const float*)d_in[5];
  const float* Wr2 = (const float*)d_in[6];
  const float* b2  = (const float*)d_in[7];
  const float* Wl3 = (const float*)d_in[8];
  const float* Wr3 = (const float*)d_in[9];
  const float* b3  = (const float*)d_in[10];

  int N = in_sizes[0] / 128;
  int E = in_sizes[1] / 2;
  const int* srcp = edges;
  const int* dstp = edges + E;

  char* ws = (char*)d_ws;
  size_t off = 0;
  auto carve = [&](size_t bytes) -> void* {
    void* p = (void*)(ws + off);
    off += (bytes + 255) & ~(size_t)255;
    return p;
  };
  int*   adj    = (int*)carve((size_t)E * 4);
  int*   rowoff = (int*)carve((size_t)(N + 1) * 4);
  int*   cnt    = (int*)carve((size_t)N * 4);
  int*   cursor = (int*)carve((size_t)N * 4);
  int*   bsum   = (int*)carve(256 * 4);
  int*   boff   = (int*)carve(256 * 4);
  float* invdeg = (float*)carve((size_t)N * 4);
  unsigned short* B1 = (unsigned short*)carve((size_t)N * 64 * 2);
  unsigned short* B2 = (unsigned short*)carve((size_t)N * 64 * 2);
  unsigned short* B3 = (unsigned short*)carve((size_t)N * 64 * 2);
  unsigned short* P  = (unsigned short*)carve((size_t)N * 128 * 2);
  (void)ws_size;

  hipMemsetAsync(cnt, 0, (size_t)N * 4, stream);
  hipMemsetAsync(cursor, 0, (size_t)N * 4, stream);

  int NB = (N + 1023) / 1024;
  int gridE = (E + THREADS - 1) / THREADS;

  count_kernel<<<gridE, THREADS, 0, stream>>>(dstp, cnt, E);
  scan1_kernel<<<NB, THREADS, 0, stream>>>(cnt, bsum, N);
  scan2_kernel<<<1, THREADS, 0, stream>>>(bsum, boff, rowoff, NB, N, E);
  scan3_kernel<<<NB, THREADS, 0, stream>>>(cnt, boff, rowoff, invdeg, N);
  fill_kernel<<<gridE, THREADS, 0, stream>>>(srcp, dstp, rowoff, cursor, adj, E);

  int gridG = (N + 127) / 128;
  int gridA = (N + 7) / 8;

  // Layer 1 (transform-first): [z1|y1] = x @ [Wl1|Wr1]^T -> B1(z1), B2(y1)   [A fp32]
  mfma_gemm<<<gridG, THREADS, 0, stream>>>(x, x + 64, 512, 512, 1, Wl1, Wr1, 0,
                                           nullptr, 0, B1, B2, 64, 64, N);
  // h1 = relu(mean(z1) + y1 + b1) -> B3
  agg_bf16<<<gridA, THREADS, 0, stream>>>(B1, adj, rowoff, invdeg, B2, b1, B3, N, 1, 0);
  // mean2 = mean(h1) -> B1
  agg_bf16<<<gridA, THREADS, 0, stream>>>(B3, adj, rowoff, invdeg, nullptr, nullptr, B1, N, 0, 0);
  // Layer 2 (aggregate-first): h2 = relu([mean2|h1] @ [Wl2,Wr2]_K^T + b2) -> P
  mfma_gemm<<<gridG, THREADS, 0, stream>>>(B1, B3, 128, 128, 0, Wl2, Wr2, 1,
                                           b2, 1, P, P + 64, 128, 128, N);
  // Layer 3 (transform-first): [z3|y3] = h2 @ [Wl3|Wr3]^T -> B2(z3), B1(y3)
  mfma_gemm<<<gridG, THREADS, 0, stream>>>(P, P + 64, 256, 256, 0, Wl3, Wr3, 0,
                                           nullptr, 0, B2, B1, 64, 64, N);
  // out = mean(z3) + y3 + b3 -> d_out (fp32)
  agg_bf16<<<gridA, THREADS, 0, stream>>>(B2, adj, rowoff, invdeg, B1, b3, d_out, N, 0, 1);
}